// Round 2
// baseline (944.030 us; speedup 1.0000x reference)
//
#include <hip/hip_runtime.h>

#define D 64
#define NNODES 100000
#define NGRAPHS 128
#define SCAN_T 1024

// ---------------- zero buffer (int4 grid-stride) ----------------
__global__ void zero_kernel(int* __restrict__ buf, int n4) {
    int i = blockIdx.x * blockDim.x + threadIdx.x;
    int stride = gridDim.x * blockDim.x;
    int4 z = make_int4(0, 0, 0, 0);
    for (; i < n4; i += stride) ((int4*)buf)[i] = z;
}

// ---------------- degree histogram ----------------
__global__ void hist_kernel(const int* __restrict__ dst, int* __restrict__ cnt, int nE) {
    int e = blockIdx.x * blockDim.x + threadIdx.x;
    if (e < nE) atomicAdd(&cnt[dst[e]], 1);
}

// ---------------- single-block exclusive scan over node degrees ----------------
// 1024 threads, each owns a contiguous chunk (~98 counters). Hillis-Steele on
// the 1024 partials in LDS, then each thread writes its chunk's running prefix
// into off[] and cursor[]. Thread SCAN_T-1 writes off[n] = total.
__global__ void scan_kernel(const int* __restrict__ cnt, int* __restrict__ off,
                            int* __restrict__ cursor, int n) {
    __shared__ int part[SCAN_T];
    int t = threadIdx.x;
    int chunk = (n + SCAN_T - 1) / SCAN_T;
    int beg = t * chunk, end = min(beg + chunk, n);
    int s = 0;
    for (int i = beg; i < end; ++i) s += cnt[i];
    part[t] = s;
    __syncthreads();
    for (int d = 1; d < SCAN_T; d <<= 1) {
        int u = (t >= d) ? part[t - d] : 0;
        __syncthreads();
        part[t] += u;
        __syncthreads();
    }
    int run = (t == 0) ? 0 : part[t - 1];   // exclusive
    for (int i = beg; i < end; ++i) {
        off[i] = run;
        cursor[i] = run;
        run += cnt[i];
    }
    if (t == SCAN_T - 1) off[n] = run;
}

// ---------------- CSR fill: esrc sorted by dst ----------------
__global__ void fill_kernel(const int* __restrict__ src, const int* __restrict__ dst,
                            int* __restrict__ cursor, int* __restrict__ esrc, int nE) {
    int e = blockIdx.x * blockDim.x + threadIdx.x;
    if (e < nE) {
        int p = atomicAdd(&cursor[dst[e]], 1);
        esrc[p] = src[e];
    }
}

// ---------------- fused gather-aggregate + (x+agg)@W + b [+relu] ----------------
// One wave per node (grid-stride). Edge loop: esrc[i] broadcast load, x row is
// one coalesced 256B load per edge; accumulate in a register. MLP via LDS:
// xs[k] broadcast (free), Ws[k*64+lane] 2-way bank alias (free on CDNA4).
template <bool RELU>
__global__ void layer_kernel(const float* __restrict__ x,
                             const int* __restrict__ off,
                             const int* __restrict__ esrc,
                             const float* __restrict__ W,
                             const float* __restrict__ b,
                             float* __restrict__ out, int n) {
    __shared__ float Ws[D * D];
    __shared__ float bs[D];
    __shared__ float xs[4][D];
    int tid = threadIdx.x;
    for (int i = tid; i < D * D / 4; i += blockDim.x)
        ((float4*)Ws)[i] = ((const float4*)W)[i];
    if (tid < D) bs[tid] = b[tid];
    __syncthreads();

    int w = tid >> 6, lane = tid & 63;
    int node = blockIdx.x * 4 + w;
    int stride = gridDim.x * 4;
    for (; node < n; node += stride) {
        float acc0 = x[(long long)node * D + lane];   // self term (eps=0)
        int beg = off[node], end = off[node + 1];
        for (int i = beg; i < end; ++i) {
            int s = esrc[i];
            acc0 += x[(long long)s * D + lane];
        }
        xs[w][lane] = acc0;
        float acc = bs[lane];
#pragma unroll
        for (int k = 0; k < D; ++k)
            acc = fmaf(xs[w][k], Ws[k * D + lane], acc);
        out[(long long)node * D + lane] = RELU ? fmaxf(acc, 0.f) : acc;
    }
}

// ------- final layer: gather-aggregate + MLP2 + sorted-segment sum pooling -------
// Chunked (not grid-stride) wave->node ranges so each wave sees contiguous,
// sorted graph_ids: register-accumulate, flush one atomicAdd per boundary.
__global__ void layer_pool_kernel(const float* __restrict__ x,
                                  const int* __restrict__ off,
                                  const int* __restrict__ esrc,
                                  const float* __restrict__ W,
                                  const float* __restrict__ b,
                                  const int* __restrict__ gid,
                                  float* __restrict__ out, int n) {
    __shared__ float Ws[D * D];
    __shared__ float bs[D];
    __shared__ float xs[4][D];
    int tid = threadIdx.x;
    for (int i = tid; i < D * D / 4; i += blockDim.x)
        ((float4*)Ws)[i] = ((const float4*)W)[i];
    if (tid < D) bs[tid] = b[tid];
    __syncthreads();

    int w = tid >> 6, lane = tid & 63;
    int waves_total = gridDim.x * 4;
    int wave_id = blockIdx.x * 4 + w;
    int chunk = (n + waves_total - 1) / waves_total;
    int start = wave_id * chunk;
    int end = min(start + chunk, n);

    float accp = 0.f;
    int cur = -1;
    for (int node = start; node < end; ++node) {
        float acc0 = x[(long long)node * D + lane];
        int ebeg = off[node], eend = off[node + 1];
        for (int i = ebeg; i < eend; ++i) {
            int s = esrc[i];
            acc0 += x[(long long)s * D + lane];
        }
        xs[w][lane] = acc0;
        float acc = bs[lane];
#pragma unroll
        for (int k = 0; k < D; ++k)
            acc = fmaf(xs[w][k], Ws[k * D + lane], acc);
        int g = gid[node];            // uniform across the wave (sorted)
        if (g != cur) {
            if (cur >= 0) atomicAdd(&out[cur * D + lane], accp);
            cur = g;
            accp = 0.f;
        }
        accp += acc;
    }
    if (cur >= 0) atomicAdd(&out[cur * D + lane], accp);
}

extern "C" void kernel_launch(void* const* d_in, const int* in_sizes, int n_in,
                              void* d_out, int out_size, void* d_ws, size_t ws_size,
                              hipStream_t stream) {
    const float* feats = (const float*)d_in[0];
    const int*   src   = (const int*)d_in[1];
    const int*   dst   = (const int*)d_in[2];
    const int*   gid   = (const int*)d_in[3];
    const float* W1    = (const float*)d_in[4];
    const float* b1    = (const float*)d_in[5];
    const float* W2    = (const float*)d_in[6];
    const float* b2    = (const float*)d_in[7];
    float* out = (float*)d_out;

    int nE = in_sizes[1];

    // workspace layout
    int*   cnt    = (int*)d_ws;                         // NNODES
    int*   off    = cnt + NNODES;                       // NNODES+1
    int*   cursor = off + NNODES + 1;                   // NNODES
    int*   esrc   = cursor + NNODES;                    // nE
    float* h      = (float*)(esrc + nE);                // NNODES*D floats

    int eBlocks = (nE + 255) / 256;

    // ---- CSR build (amortized over both layers) ----
    zero_kernel<<<256, 256, 0, stream>>>(cnt, NNODES / 4);
    hist_kernel<<<eBlocks, 256, 0, stream>>>(dst, cnt, nE);
    scan_kernel<<<1, SCAN_T, 0, stream>>>(cnt, off, cursor, NNODES);
    fill_kernel<<<eBlocks, 256, 0, stream>>>(src, dst, cursor, esrc, nE);

    // ---- layer 1: h = relu((feats + gather) @ W1 + b1) ----
    layer_kernel<true><<<2048, 256, 0, stream>>>(feats, off, esrc, W1, b1, h, NNODES);

    // ---- layer 2 + pooling ----
    zero_kernel<<<16, 256, 0, stream>>>((int*)out, NGRAPHS * D / 4);
    layer_pool_kernel<<<512, 256, 0, stream>>>(h, off, esrc, W2, b2, gid, out, NNODES);
}

// Round 3
// 578.751 us; speedup vs baseline: 1.6312x; 1.6312x over previous
//
#include <hip/hip_runtime.h>

#define D 64
#define NNODES 100000
#define NGRAPHS 128
#define SCAN_T 1024

// ---------------- zero buffer (int4 grid-stride) ----------------
__global__ void zero_kernel(int* __restrict__ buf, int n4) {
    int i = blockIdx.x * blockDim.x + threadIdx.x;
    int stride = gridDim.x * blockDim.x;
    int4 z = make_int4(0, 0, 0, 0);
    for (; i < n4; i += stride) ((int4*)buf)[i] = z;
}

// ---------------- degree histogram ----------------
__global__ void hist_kernel(const int* __restrict__ dst, int* __restrict__ cnt, int nE) {
    int e = blockIdx.x * blockDim.x + threadIdx.x;
    if (e < nE) atomicAdd(&cnt[dst[e]], 1);
}

// ---------------- single-block exclusive scan over node degrees ----------------
__global__ void scan_kernel(const int* __restrict__ cnt, int* __restrict__ off,
                            int* __restrict__ cursor, int n) {
    __shared__ int part[SCAN_T];
    int t = threadIdx.x;
    int chunk = (n + SCAN_T - 1) / SCAN_T;
    int beg = t * chunk, end = min(beg + chunk, n);
    int s = 0;
    for (int i = beg; i < end; ++i) s += cnt[i];
    part[t] = s;
    __syncthreads();
    for (int d = 1; d < SCAN_T; d <<= 1) {
        int u = (t >= d) ? part[t - d] : 0;
        __syncthreads();
        part[t] += u;
        __syncthreads();
    }
    int run = (t == 0) ? 0 : part[t - 1];   // exclusive
    for (int i = beg; i < end; ++i) {
        off[i] = run;
        cursor[i] = run;
        run += cnt[i];
    }
    if (t == SCAN_T - 1) off[n] = run;
}

// ---------------- CSR fill: esrc sorted by dst ----------------
__global__ void fill_kernel(const int* __restrict__ src, const int* __restrict__ dst,
                            int* __restrict__ cursor, int* __restrict__ esrc, int nE) {
    int e = blockIdx.x * blockDim.x + threadIdx.x;
    if (e < nE) {
        int p = atomicAdd(&cursor[dst[e]], 1);
        esrc[p] = src[e];
    }
}

// ---- gather with 8/4-wide ILP: batch index loads, then independent row loads ----
__device__ __forceinline__ float gather_row(const float* __restrict__ x,
                                            const int* __restrict__ esrc,
                                            int beg, int end, int lane, float acc) {
    int i = beg;
    while (i + 8 <= end) {
        int s0 = esrc[i + 0], s1 = esrc[i + 1], s2 = esrc[i + 2], s3 = esrc[i + 3];
        int s4 = esrc[i + 4], s5 = esrc[i + 5], s6 = esrc[i + 6], s7 = esrc[i + 7];
        float v0 = x[(size_t)s0 * D + lane], v1 = x[(size_t)s1 * D + lane];
        float v2 = x[(size_t)s2 * D + lane], v3 = x[(size_t)s3 * D + lane];
        float v4 = x[(size_t)s4 * D + lane], v5 = x[(size_t)s5 * D + lane];
        float v6 = x[(size_t)s6 * D + lane], v7 = x[(size_t)s7 * D + lane];
        acc += ((v0 + v1) + (v2 + v3)) + ((v4 + v5) + (v6 + v7));
        i += 8;
    }
    if (i + 4 <= end) {
        int s0 = esrc[i + 0], s1 = esrc[i + 1], s2 = esrc[i + 2], s3 = esrc[i + 3];
        float v0 = x[(size_t)s0 * D + lane], v1 = x[(size_t)s1 * D + lane];
        float v2 = x[(size_t)s2 * D + lane], v3 = x[(size_t)s3 * D + lane];
        acc += (v0 + v1) + (v2 + v3);
        i += 4;
    }
    for (; i < end; ++i) acc += x[(size_t)esrc[i] * D + lane];
    return acc;
}

// ---------------- fused gather-aggregate + (x+agg)@W + b [+relu] ----------------
template <bool RELU>
__global__ void layer_kernel(const float* __restrict__ x,
                             const int* __restrict__ off,
                             const int* __restrict__ esrc,
                             const float* __restrict__ W,
                             const float* __restrict__ b,
                             float* __restrict__ out, int n) {
    __shared__ float Ws[D * D];
    __shared__ float bs[D];
    __shared__ float xs[4][D];
    int tid = threadIdx.x;
    for (int i = tid; i < D * D / 4; i += blockDim.x)
        ((float4*)Ws)[i] = ((const float4*)W)[i];
    if (tid < D) bs[tid] = b[tid];
    __syncthreads();

    int w = tid >> 6, lane = tid & 63;
    int node = blockIdx.x * 4 + w;
    int stride = gridDim.x * 4;
    for (; node < n; node += stride) {
        float acc0 = x[(long long)node * D + lane];   // self term (eps=0)
        acc0 = gather_row(x, esrc, off[node], off[node + 1], lane, acc0);
        xs[w][lane] = acc0;
        float acc = bs[lane];
#pragma unroll
        for (int k = 0; k < D; ++k)
            acc = fmaf(xs[w][k], Ws[k * D + lane], acc);
        out[(long long)node * D + lane] = RELU ? fmaxf(acc, 0.f) : acc;
    }
}

// ------- final layer: gather-aggregate + MLP2 + sorted-segment sum pooling -------
__global__ void layer_pool_kernel(const float* __restrict__ x,
                                  const int* __restrict__ off,
                                  const int* __restrict__ esrc,
                                  const float* __restrict__ W,
                                  const float* __restrict__ b,
                                  const int* __restrict__ gid,
                                  float* __restrict__ out, int n) {
    __shared__ float Ws[D * D];
    __shared__ float bs[D];
    __shared__ float xs[4][D];
    int tid = threadIdx.x;
    for (int i = tid; i < D * D / 4; i += blockDim.x)
        ((float4*)Ws)[i] = ((const float4*)W)[i];
    if (tid < D) bs[tid] = b[tid];
    __syncthreads();

    int w = tid >> 6, lane = tid & 63;
    int waves_total = gridDim.x * 4;
    int wave_id = blockIdx.x * 4 + w;
    int chunk = (n + waves_total - 1) / waves_total;
    int start = wave_id * chunk;
    int end = min(start + chunk, n);

    float accp = 0.f;
    int cur = -1;
    for (int node = start; node < end; ++node) {
        float acc0 = x[(long long)node * D + lane];
        acc0 = gather_row(x, esrc, off[node], off[node + 1], lane, acc0);
        xs[w][lane] = acc0;
        float acc = bs[lane];
#pragma unroll
        for (int k = 0; k < D; ++k)
            acc = fmaf(xs[w][k], Ws[k * D + lane], acc);
        int g = gid[node];            // uniform across the wave (sorted)
        if (g != cur) {
            if (cur >= 0) atomicAdd(&out[cur * D + lane], accp);
            cur = g;
            accp = 0.f;
        }
        accp += acc;
    }
    if (cur >= 0) atomicAdd(&out[cur * D + lane], accp);
}

extern "C" void kernel_launch(void* const* d_in, const int* in_sizes, int n_in,
                              void* d_out, int out_size, void* d_ws, size_t ws_size,
                              hipStream_t stream) {
    const float* feats = (const float*)d_in[0];
    const int*   src   = (const int*)d_in[1];
    const int*   dst   = (const int*)d_in[2];
    const int*   gid   = (const int*)d_in[3];
    const float* W1    = (const float*)d_in[4];
    const float* b1    = (const float*)d_in[5];
    const float* W2    = (const float*)d_in[6];
    const float* b2    = (const float*)d_in[7];
    float* out = (float*)d_out;

    int nE = in_sizes[1];

    // workspace layout
    int*   cnt    = (int*)d_ws;                         // NNODES
    int*   off    = cnt + NNODES;                       // NNODES+1
    int*   cursor = off + NNODES + 1;                   // NNODES
    int*   esrc   = cursor + NNODES;                    // nE
    float* h      = (float*)(esrc + nE);                // NNODES*D floats

    int eBlocks = (nE + 255) / 256;

    // ---- CSR build (amortized over both layers) ----
    zero_kernel<<<256, 256, 0, stream>>>(cnt, NNODES / 4);
    hist_kernel<<<eBlocks, 256, 0, stream>>>(dst, cnt, nE);
    scan_kernel<<<1, SCAN_T, 0, stream>>>(cnt, off, cursor, NNODES);
    fill_kernel<<<eBlocks, 256, 0, stream>>>(src, dst, cursor, esrc, nE);

    // ---- layer 1: h = relu((feats + gather) @ W1 + b1) ----
    layer_kernel<true><<<2048, 256, 0, stream>>>(feats, off, esrc, W1, b1, h, NNODES);

    // ---- layer 2 + pooling (full occupancy: 2048 blocks = 8/CU) ----
    zero_kernel<<<16, 256, 0, stream>>>((int*)out, NGRAPHS * D / 4);
    layer_pool_kernel<<<2048, 256, 0, stream>>>(h, off, esrc, W2, b2, gid, out, NNODES);
}

// Round 4
// 361.771 us; speedup vs baseline: 2.6095x; 1.5998x over previous
//
#include <hip/hip_runtime.h>

#define D 64
#define NNODES 100000
#define NGRAPHS 128

// ---------------- zero buffer (int4 grid-stride) ----------------
__global__ void zero_kernel(int* __restrict__ buf, int n4) {
    int i = blockIdx.x * blockDim.x + threadIdx.x;
    int stride = gridDim.x * blockDim.x;
    int4 z = make_int4(0, 0, 0, 0);
    for (; i < n4; i += stride) ((int4*)buf)[i] = z;
}

// ---------------- degree histogram ----------------
__global__ void hist_kernel(const int* __restrict__ dst, int* __restrict__ cnt, int nE) {
    int e = blockIdx.x * blockDim.x + threadIdx.x;
    if (e < nE) atomicAdd(&cnt[dst[e]], 1);
}

// ---------------- 3-phase parallel exclusive scan ----------------
// Phase A: per-block coalesced reduction of cnt -> bsum[block]
__global__ void partial_kernel(const int* __restrict__ cnt, int* __restrict__ bsum, int n) {
    __shared__ int sh[256];
    int t = threadIdx.x;
    int i = blockIdx.x * 256 + t;
    sh[t] = (i < n) ? cnt[i] : 0;
    __syncthreads();
    for (int d = 128; d > 0; d >>= 1) {
        if (t < d) sh[t] += sh[t + d];
        __syncthreads();
    }
    if (t == 0) bsum[blockIdx.x] = sh[0];
}

// Phase B: one small block scans the <=512 block sums (exclusive)
__global__ void scanb_kernel(const int* __restrict__ bsum, int* __restrict__ bbase, int nb) {
    __shared__ int sh[512];
    int t = threadIdx.x;
    sh[t] = (t < nb) ? bsum[t] : 0;
    __syncthreads();
    for (int d = 1; d < 512; d <<= 1) {
        int u = (t >= d) ? sh[t - d] : 0;
        __syncthreads();
        sh[t] += u;
        __syncthreads();
    }
    if (t < nb) bbase[t] = (t == 0) ? 0 : sh[t - 1];
}

// Phase C: per-block local exclusive scan + block base -> off[], cursor[]
__global__ void offsets_kernel(const int* __restrict__ cnt, const int* __restrict__ bbase,
                               int* __restrict__ off, int* __restrict__ cursor, int n) {
    __shared__ int sh[256];
    int t = threadIdx.x;
    int i = blockIdx.x * 256 + t;
    int v = (i < n) ? cnt[i] : 0;
    sh[t] = v;
    __syncthreads();
    for (int d = 1; d < 256; d <<= 1) {
        int u = (t >= d) ? sh[t - d] : 0;
        __syncthreads();
        sh[t] += u;
        __syncthreads();
    }
    int excl = bbase[blockIdx.x] + sh[t] - v;
    if (i < n) {
        off[i] = excl;
        cursor[i] = excl;
        if (i == n - 1) off[n] = excl + v;
    }
}

// ---------------- CSR fill: esrc sorted by dst ----------------
__global__ void fill_kernel(const int* __restrict__ src, const int* __restrict__ dst,
                            int* __restrict__ cursor, int* __restrict__ esrc, int nE) {
    int e = blockIdx.x * blockDim.x + threadIdx.x;
    if (e < nE) {
        int p = atomicAdd(&cursor[dst[e]], 1);
        esrc[p] = src[e];
    }
}

// ---- gather with 8/4-wide ILP: batch index loads, then independent row loads ----
__device__ __forceinline__ float gather_row(const float* __restrict__ x,
                                            const int* __restrict__ esrc,
                                            int beg, int end, int lane, float acc) {
    int i = beg;
    while (i + 8 <= end) {
        int s0 = esrc[i + 0], s1 = esrc[i + 1], s2 = esrc[i + 2], s3 = esrc[i + 3];
        int s4 = esrc[i + 4], s5 = esrc[i + 5], s6 = esrc[i + 6], s7 = esrc[i + 7];
        float v0 = x[(size_t)s0 * D + lane], v1 = x[(size_t)s1 * D + lane];
        float v2 = x[(size_t)s2 * D + lane], v3 = x[(size_t)s3 * D + lane];
        float v4 = x[(size_t)s4 * D + lane], v5 = x[(size_t)s5 * D + lane];
        float v6 = x[(size_t)s6 * D + lane], v7 = x[(size_t)s7 * D + lane];
        acc += ((v0 + v1) + (v2 + v3)) + ((v4 + v5) + (v6 + v7));
        i += 8;
    }
    if (i + 4 <= end) {
        int s0 = esrc[i + 0], s1 = esrc[i + 1], s2 = esrc[i + 2], s3 = esrc[i + 3];
        float v0 = x[(size_t)s0 * D + lane], v1 = x[(size_t)s1 * D + lane];
        float v2 = x[(size_t)s2 * D + lane], v3 = x[(size_t)s3 * D + lane];
        acc += (v0 + v1) + (v2 + v3);
        i += 4;
    }
    for (; i < end; ++i) acc += x[(size_t)esrc[i] * D + lane];
    return acc;
}

// ---------------- fused gather-aggregate + (x+agg)@W + b [+relu] ----------------
template <bool RELU>
__global__ void layer_kernel(const float* __restrict__ x,
                             const int* __restrict__ off,
                             const int* __restrict__ esrc,
                             const float* __restrict__ W,
                             const float* __restrict__ b,
                             float* __restrict__ out, int n) {
    __shared__ float Ws[D * D];
    __shared__ float bs[D];
    __shared__ float xs[4][D];
    int tid = threadIdx.x;
    for (int i = tid; i < D * D / 4; i += blockDim.x)
        ((float4*)Ws)[i] = ((const float4*)W)[i];
    if (tid < D) bs[tid] = b[tid];
    __syncthreads();

    int w = tid >> 6, lane = tid & 63;
    int node = blockIdx.x * 4 + w;
    int stride = gridDim.x * 4;
    for (; node < n; node += stride) {
        float acc0 = x[(long long)node * D + lane];   // self term (eps=0)
        acc0 = gather_row(x, esrc, off[node], off[node + 1], lane, acc0);
        xs[w][lane] = acc0;
        float acc = bs[lane];
#pragma unroll
        for (int k = 0; k < D; ++k)
            acc = fmaf(xs[w][k], Ws[k * D + lane], acc);
        out[(long long)node * D + lane] = RELU ? fmaxf(acc, 0.f) : acc;
    }
}

// ------- final layer: gather-aggregate + MLP2 + sorted-segment sum pooling -------
__global__ void layer_pool_kernel(const float* __restrict__ x,
                                  const int* __restrict__ off,
                                  const int* __restrict__ esrc,
                                  const float* __restrict__ W,
                                  const float* __restrict__ b,
                                  const int* __restrict__ gid,
                                  float* __restrict__ out, int n) {
    __shared__ float Ws[D * D];
    __shared__ float bs[D];
    __shared__ float xs[4][D];
    int tid = threadIdx.x;
    for (int i = tid; i < D * D / 4; i += blockDim.x)
        ((float4*)Ws)[i] = ((const float4*)W)[i];
    if (tid < D) bs[tid] = b[tid];
    __syncthreads();

    int w = tid >> 6, lane = tid & 63;
    int waves_total = gridDim.x * 4;
    int wave_id = blockIdx.x * 4 + w;
    int chunk = (n + waves_total - 1) / waves_total;
    int start = wave_id * chunk;
    int end = min(start + chunk, n);

    float accp = 0.f;
    int cur = -1;
    for (int node = start; node < end; ++node) {
        float acc0 = x[(long long)node * D + lane];
        acc0 = gather_row(x, esrc, off[node], off[node + 1], lane, acc0);
        xs[w][lane] = acc0;
        float acc = bs[lane];
#pragma unroll
        for (int k = 0; k < D; ++k)
            acc = fmaf(xs[w][k], Ws[k * D + lane], acc);
        int g = gid[node];            // uniform across the wave (sorted)
        if (g != cur) {
            if (cur >= 0) atomicAdd(&out[cur * D + lane], accp);
            cur = g;
            accp = 0.f;
        }
        accp += acc;
    }
    if (cur >= 0) atomicAdd(&out[cur * D + lane], accp);
}

extern "C" void kernel_launch(void* const* d_in, const int* in_sizes, int n_in,
                              void* d_out, int out_size, void* d_ws, size_t ws_size,
                              hipStream_t stream) {
    const float* feats = (const float*)d_in[0];
    const int*   src   = (const int*)d_in[1];
    const int*   dst   = (const int*)d_in[2];
    const int*   gid   = (const int*)d_in[3];
    const float* W1    = (const float*)d_in[4];
    const float* b1    = (const float*)d_in[5];
    const float* W2    = (const float*)d_in[6];
    const float* b2    = (const float*)d_in[7];
    float* out = (float*)d_out;

    int nE = in_sizes[1];
    int nBlocksN = (NNODES + 255) / 256;    // 391

    // workspace layout
    int*   cnt    = (int*)d_ws;                         // NNODES
    int*   off    = cnt + NNODES;                       // NNODES+1
    int*   cursor = off + NNODES + 1;                   // NNODES
    int*   bsum   = cursor + NNODES;                    // nBlocksN
    int*   bbase  = bsum + nBlocksN;                    // nBlocksN
    int*   esrc   = bbase + nBlocksN;                   // nE
    float* h      = (float*)(esrc + nE);                // NNODES*D floats

    int eBlocks = (nE + 255) / 256;

    // ---- CSR build ----
    zero_kernel<<<256, 256, 0, stream>>>(cnt, NNODES / 4);
    hist_kernel<<<eBlocks, 256, 0, stream>>>(dst, cnt, nE);
    partial_kernel<<<nBlocksN, 256, 0, stream>>>(cnt, bsum, NNODES);
    scanb_kernel<<<1, 512, 0, stream>>>(bsum, bbase, nBlocksN);
    offsets_kernel<<<nBlocksN, 256, 0, stream>>>(cnt, bbase, off, cursor, NNODES);
    fill_kernel<<<eBlocks, 256, 0, stream>>>(src, dst, cursor, esrc, nE);

    // ---- layer 1: h = relu((feats + gather) @ W1 + b1) ----
    layer_kernel<true><<<2048, 256, 0, stream>>>(feats, off, esrc, W1, b1, h, NNODES);

    // ---- layer 2 + pooling ----
    zero_kernel<<<16, 256, 0, stream>>>((int*)out, NGRAPHS * D / 4);
    layer_pool_kernel<<<2048, 256, 0, stream>>>(h, off, esrc, W2, b2, gid, out, NNODES);
}

// Round 5
// 358.684 us; speedup vs baseline: 2.6319x; 1.0086x over previous
//
#include <hip/hip_runtime.h>

#define D 64
#define NNODES 100000
#define NGRAPHS 128

typedef unsigned int uint;
typedef unsigned short ushort;

// ---- bf16 helpers (RNE), kept as raw ushort to avoid type ceremony ----
__device__ __forceinline__ ushort f2b(float f) {
    uint u = __float_as_uint(f);
    uint r = (u + 0x7fffu + ((u >> 16) & 1u)) >> 16;
    return (ushort)r;
}
__device__ __forceinline__ float b2f(ushort h) {
    return __uint_as_float(((uint)h) << 16);
}

// ---------------- zero buffer (int4 grid-stride) ----------------
__global__ void zero_kernel(int* __restrict__ buf, int n4) {
    int i = blockIdx.x * blockDim.x + threadIdx.x;
    int stride = gridDim.x * blockDim.x;
    int4 z = make_int4(0, 0, 0, 0);
    for (; i < n4; i += stride) ((int4*)buf)[i] = z;
}

// ---------------- f32 -> bf16 cast (float4 in, ushort4 out) ----------------
__global__ void cast_kernel(const float* __restrict__ in, ushort* __restrict__ outb, int n4) {
    int i = blockIdx.x * blockDim.x + threadIdx.x;
    int stride = gridDim.x * blockDim.x;
    for (; i < n4; i += stride) {
        float4 v = ((const float4*)in)[i];
        ushort4 o;
        o.x = f2b(v.x); o.y = f2b(v.y); o.z = f2b(v.z); o.w = f2b(v.w);
        ((ushort4*)outb)[i] = o;
    }
}

// ---------------- degree histogram (int4 edge loads) ----------------
__global__ void hist_kernel(const int* __restrict__ dst, int* __restrict__ cnt, int nE) {
    int i = blockIdx.x * blockDim.x + threadIdx.x;
    int base = i * 4;
    if (base + 4 <= nE) {
        int4 d = *(const int4*)(dst + base);
        atomicAdd(&cnt[d.x], 1);
        atomicAdd(&cnt[d.y], 1);
        atomicAdd(&cnt[d.z], 1);
        atomicAdd(&cnt[d.w], 1);
    } else {
        for (int e = base; e < nE; ++e) atomicAdd(&cnt[dst[e]], 1);
    }
}

// ---------------- 3-phase parallel exclusive scan ----------------
__global__ void partial_kernel(const int* __restrict__ cnt, int* __restrict__ bsum, int n) {
    __shared__ int sh[256];
    int t = threadIdx.x;
    int i = blockIdx.x * 256 + t;
    sh[t] = (i < n) ? cnt[i] : 0;
    __syncthreads();
    for (int d = 128; d > 0; d >>= 1) {
        if (t < d) sh[t] += sh[t + d];
        __syncthreads();
    }
    if (t == 0) bsum[blockIdx.x] = sh[0];
}

__global__ void scanb_kernel(const int* __restrict__ bsum, int* __restrict__ bbase, int nb) {
    __shared__ int sh[512];
    int t = threadIdx.x;
    sh[t] = (t < nb) ? bsum[t] : 0;
    __syncthreads();
    for (int d = 1; d < 512; d <<= 1) {
        int u = (t >= d) ? sh[t - d] : 0;
        __syncthreads();
        sh[t] += u;
        __syncthreads();
    }
    if (t < nb) bbase[t] = (t == 0) ? 0 : sh[t - 1];
}

__global__ void offsets_kernel(const int* __restrict__ cnt, const int* __restrict__ bbase,
                               int* __restrict__ off, int* __restrict__ cursor, int n) {
    __shared__ int sh[256];
    int t = threadIdx.x;
    int i = blockIdx.x * 256 + t;
    int v = (i < n) ? cnt[i] : 0;
    sh[t] = v;
    __syncthreads();
    for (int d = 1; d < 256; d <<= 1) {
        int u = (t >= d) ? sh[t - d] : 0;
        __syncthreads();
        sh[t] += u;
        __syncthreads();
    }
    int excl = bbase[blockIdx.x] + sh[t] - v;
    if (i < n) {
        off[i] = excl;
        cursor[i] = excl;
        if (i == n - 1) off[n] = excl + v;
    }
}

// ---------------- CSR fill (int4 edge loads): esrc sorted by dst ----------------
__global__ void fill_kernel(const int* __restrict__ src, const int* __restrict__ dst,
                            int* __restrict__ cursor, int* __restrict__ esrc, int nE) {
    int i = blockIdx.x * blockDim.x + threadIdx.x;
    int base = i * 4;
    if (base + 4 <= nE) {
        int4 d = *(const int4*)(dst + base);
        int4 s = *(const int4*)(src + base);
        esrc[atomicAdd(&cursor[d.x], 1)] = s.x;
        esrc[atomicAdd(&cursor[d.y], 1)] = s.y;
        esrc[atomicAdd(&cursor[d.z], 1)] = s.z;
        esrc[atomicAdd(&cursor[d.w], 1)] = s.w;
    } else {
        for (int e = base; e < nE; ++e) {
            int p = atomicAdd(&cursor[dst[e]], 1);
            esrc[p] = src[e];
        }
    }
}

// ---- bf16 gather with 8/4-wide ILP: one cache line per edge row ----
__device__ __forceinline__ float gather_row_b(const ushort* __restrict__ x,
                                              const int* __restrict__ esrc,
                                              int beg, int end, int lane, float acc) {
    int i = beg;
    while (i + 8 <= end) {
        int s0 = esrc[i + 0], s1 = esrc[i + 1], s2 = esrc[i + 2], s3 = esrc[i + 3];
        int s4 = esrc[i + 4], s5 = esrc[i + 5], s6 = esrc[i + 6], s7 = esrc[i + 7];
        ushort v0 = x[(size_t)s0 * D + lane], v1 = x[(size_t)s1 * D + lane];
        ushort v2 = x[(size_t)s2 * D + lane], v3 = x[(size_t)s3 * D + lane];
        ushort v4 = x[(size_t)s4 * D + lane], v5 = x[(size_t)s5 * D + lane];
        ushort v6 = x[(size_t)s6 * D + lane], v7 = x[(size_t)s7 * D + lane];
        acc += ((b2f(v0) + b2f(v1)) + (b2f(v2) + b2f(v3))) +
               ((b2f(v4) + b2f(v5)) + (b2f(v6) + b2f(v7)));
        i += 8;
    }
    if (i + 4 <= end) {
        int s0 = esrc[i + 0], s1 = esrc[i + 1], s2 = esrc[i + 2], s3 = esrc[i + 3];
        ushort v0 = x[(size_t)s0 * D + lane], v1 = x[(size_t)s1 * D + lane];
        ushort v2 = x[(size_t)s2 * D + lane], v3 = x[(size_t)s3 * D + lane];
        acc += (b2f(v0) + b2f(v1)) + (b2f(v2) + b2f(v3));
        i += 4;
    }
    for (; i < end; ++i) acc += b2f(x[(size_t)esrc[i] * D + lane]);
    return acc;
}

// ---------------- fused gather + (x+agg)@W + b + relu, bf16 in/out ----------------
__global__ void layer1_kernel(const ushort* __restrict__ xb,
                              const int* __restrict__ off,
                              const int* __restrict__ esrc,
                              const float* __restrict__ W,
                              const float* __restrict__ b,
                              ushort* __restrict__ outb, int n) {
    __shared__ float Ws[D * D];
    __shared__ float bs[D];
    __shared__ float xs[4][D];
    int tid = threadIdx.x;
    for (int i = tid; i < D * D / 4; i += blockDim.x)
        ((float4*)Ws)[i] = ((const float4*)W)[i];
    if (tid < D) bs[tid] = b[tid];
    __syncthreads();

    int w = tid >> 6, lane = tid & 63;
    int node = blockIdx.x * 4 + w;
    int stride = gridDim.x * 4;
    for (; node < n; node += stride) {
        float acc0 = b2f(xb[(size_t)node * D + lane]);   // self term (eps=0)
        acc0 = gather_row_b(xb, esrc, off[node], off[node + 1], lane, acc0);
        xs[w][lane] = acc0;
        float acc = bs[lane];
#pragma unroll
        for (int k = 0; k < D; ++k)
            acc = fmaf(xs[w][k], Ws[k * D + lane], acc);
        outb[(size_t)node * D + lane] = f2b(fmaxf(acc, 0.f));
    }
}

// ------- final layer: bf16 gather + MLP2 + sorted-segment sum pooling (f32 out) -------
__global__ void layer_pool_kernel(const ushort* __restrict__ xb,
                                  const int* __restrict__ off,
                                  const int* __restrict__ esrc,
                                  const float* __restrict__ W,
                                  const float* __restrict__ b,
                                  const int* __restrict__ gid,
                                  float* __restrict__ out, int n) {
    __shared__ float Ws[D * D];
    __shared__ float bs[D];
    __shared__ float xs[4][D];
    int tid = threadIdx.x;
    for (int i = tid; i < D * D / 4; i += blockDim.x)
        ((float4*)Ws)[i] = ((const float4*)W)[i];
    if (tid < D) bs[tid] = b[tid];
    __syncthreads();

    int w = tid >> 6, lane = tid & 63;
    int waves_total = gridDim.x * 4;
    int wave_id = blockIdx.x * 4 + w;
    int chunk = (n + waves_total - 1) / waves_total;
    int start = wave_id * chunk;
    int end = min(start + chunk, n);

    float accp = 0.f;
    int cur = -1;
    for (int node = start; node < end; ++node) {
        float acc0 = b2f(xb[(size_t)node * D + lane]);
        acc0 = gather_row_b(xb, esrc, off[node], off[node + 1], lane, acc0);
        xs[w][lane] = acc0;
        float acc = bs[lane];
#pragma unroll
        for (int k = 0; k < D; ++k)
            acc = fmaf(xs[w][k], Ws[k * D + lane], acc);
        int g = gid[node];            // uniform across the wave (sorted)
        if (g != cur) {
            if (cur >= 0) atomicAdd(&out[cur * D + lane], accp);
            cur = g;
            accp = 0.f;
        }
        accp += acc;
    }
    if (cur >= 0) atomicAdd(&out[cur * D + lane], accp);
}

extern "C" void kernel_launch(void* const* d_in, const int* in_sizes, int n_in,
                              void* d_out, int out_size, void* d_ws, size_t ws_size,
                              hipStream_t stream) {
    const float* feats = (const float*)d_in[0];
    const int*   src   = (const int*)d_in[1];
    const int*   dst   = (const int*)d_in[2];
    const int*   gid   = (const int*)d_in[3];
    const float* W1    = (const float*)d_in[4];
    const float* b1    = (const float*)d_in[5];
    const float* W2    = (const float*)d_in[6];
    const float* b2    = (const float*)d_in[7];
    float* out = (float*)d_out;

    int nE = in_sizes[1];
    int nBlocksN = (NNODES + 255) / 256;    // 391

    // workspace layout (all segments 16B-aligned)
    int*    cnt    = (int*)d_ws;                        // 100000 ints
    int*    off    = cnt + NNODES;                      // 100004 ints (padded)
    int*    cursor = off + 100004;                      // 100000 ints
    int*    bsum   = cursor + NNODES;                   // 400 ints
    int*    bbase  = bsum + 400;                        // 400 ints
    int*    esrc   = bbase + 400;                       // nE ints
    ushort* xb     = (ushort*)(esrc + ((nE + 3) & ~3)); // NNODES*D bf16
    ushort* hb     = xb + (size_t)NNODES * D;           // NNODES*D bf16

    int e4Blocks = (nE / 4 + 256) / 256;

    // ---- CSR build ----
    zero_kernel<<<256, 256, 0, stream>>>(cnt, NNODES / 4);
    hist_kernel<<<e4Blocks, 256, 0, stream>>>(dst, cnt, nE);
    partial_kernel<<<nBlocksN, 256, 0, stream>>>(cnt, bsum, NNODES);
    scanb_kernel<<<1, 512, 0, stream>>>(bsum, bbase, nBlocksN);
    offsets_kernel<<<nBlocksN, 256, 0, stream>>>(cnt, bbase, off, cursor, NNODES);
    fill_kernel<<<e4Blocks, 256, 0, stream>>>(src, dst, cursor, esrc, nE);

    // ---- cast feats to bf16 (one cache line per row) ----
    cast_kernel<<<2048, 256, 0, stream>>>(feats, xb, NNODES * D / 4);

    // ---- layer 1: hb = bf16(relu((x + gather) @ W1 + b1)) ----
    layer1_kernel<<<2048, 256, 0, stream>>>(xb, off, esrc, W1, b1, hb, NNODES);

    // ---- layer 2 + pooling ----
    zero_kernel<<<16, 256, 0, stream>>>((int*)out, NGRAPHS * D / 4);
    layer_pool_kernel<<<2048, 256, 0, stream>>>(hb, off, esrc, W2, b2, gid, out, NNODES);
}

// Round 6
// 283.100 us; speedup vs baseline: 3.3346x; 1.2670x over previous
//
#include <hip/hip_runtime.h>

#define D 64
#define NNODES 100000
#define NGRAPHS 128
#define NTILES ((NNODES + 15) / 16)   // 6250

typedef unsigned int uint;
typedef unsigned short ushort;
typedef __attribute__((ext_vector_type(8))) short short8;   // 8 bf16 (4 VGPRs)
typedef __attribute__((ext_vector_type(4))) float f32x4;

// ---- bf16 helpers (RNE) ----
__device__ __forceinline__ ushort f2b(float f) {
    uint u = __float_as_uint(f);
    uint r = (u + 0x7fffu + ((u >> 16) & 1u)) >> 16;
    return (ushort)r;
}
__device__ __forceinline__ float b2f(ushort h) {
    return __uint_as_float(((uint)h) << 16);
}

// ---------------- zero buffer (int4 grid-stride) ----------------
__global__ void zero_kernel(int* __restrict__ buf, int n4) {
    int i = blockIdx.x * blockDim.x + threadIdx.x;
    int stride = gridDim.x * blockDim.x;
    int4 z = make_int4(0, 0, 0, 0);
    for (; i < n4; i += stride) ((int4*)buf)[i] = z;
}

// ---------------- f32 -> bf16 cast (float4 in, ushort4 out) ----------------
__global__ void cast_kernel(const float* __restrict__ in, ushort* __restrict__ outb, int n4) {
    int i = blockIdx.x * blockDim.x + threadIdx.x;
    int stride = gridDim.x * blockDim.x;
    for (; i < n4; i += stride) {
        float4 v = ((const float4*)in)[i];
        ushort4 o;
        o.x = f2b(v.x); o.y = f2b(v.y); o.z = f2b(v.z); o.w = f2b(v.w);
        ((ushort4*)outb)[i] = o;
    }
}

// -------- swizzle W1 (f32 [k][col] row-major) into MFMA B-fragment order --------
// frag j = c*2+h (col-tile c, k-half h): lane holds B[k=(lane>>4)*8+i+32h][col=16c+(lane&15)]
// Wswz[(j*64 + lane)*8 + i]
__global__ void prep_w_kernel(const float* __restrict__ W, ushort* __restrict__ Wswz) {
    int t = threadIdx.x;            // 0..511 = j*64 + lane
    int j = t >> 6, lane = t & 63;
    int c = j >> 1, h = j & 1;
    int col = 16 * c + (lane & 15);
    int kbase = (lane >> 4) * 8 + 32 * h;
#pragma unroll
    for (int i = 0; i < 8; ++i)
        Wswz[(size_t)t * 8 + i] = f2b(W[(kbase + i) * D + col]);
}

// ---------------- degree histogram (int4 edge loads) ----------------
__global__ void hist_kernel(const int* __restrict__ dst, int* __restrict__ cnt, int nE) {
    int i = blockIdx.x * blockDim.x + threadIdx.x;
    int base = i * 4;
    if (base + 4 <= nE) {
        int4 d = *(const int4*)(dst + base);
        atomicAdd(&cnt[d.x], 1);
        atomicAdd(&cnt[d.y], 1);
        atomicAdd(&cnt[d.z], 1);
        atomicAdd(&cnt[d.w], 1);
    } else {
        for (int e = base; e < nE; ++e) atomicAdd(&cnt[dst[e]], 1);
    }
}

// ---------------- 3-phase parallel exclusive scan ----------------
__global__ void partial_kernel(const int* __restrict__ cnt, int* __restrict__ bsum, int n) {
    __shared__ int sh[256];
    int t = threadIdx.x;
    int i = blockIdx.x * 256 + t;
    sh[t] = (i < n) ? cnt[i] : 0;
    __syncthreads();
    for (int d = 128; d > 0; d >>= 1) {
        if (t < d) sh[t] += sh[t + d];
        __syncthreads();
    }
    if (t == 0) bsum[blockIdx.x] = sh[0];
}

__global__ void scanb_kernel(const int* __restrict__ bsum, int* __restrict__ bbase, int nb) {
    __shared__ int sh[512];
    int t = threadIdx.x;
    sh[t] = (t < nb) ? bsum[t] : 0;
    __syncthreads();
    for (int d = 1; d < 512; d <<= 1) {
        int u = (t >= d) ? sh[t - d] : 0;
        __syncthreads();
        sh[t] += u;
        __syncthreads();
    }
    if (t < nb) bbase[t] = (t == 0) ? 0 : sh[t - 1];
}

__global__ void offsets_kernel(const int* __restrict__ cnt, const int* __restrict__ bbase,
                               int* __restrict__ off, int* __restrict__ cursor, int n) {
    __shared__ int sh[256];
    int t = threadIdx.x;
    int i = blockIdx.x * 256 + t;
    int v = (i < n) ? cnt[i] : 0;
    sh[t] = v;
    __syncthreads();
    for (int d = 1; d < 256; d <<= 1) {
        int u = (t >= d) ? sh[t - d] : 0;
        __syncthreads();
        sh[t] += u;
        __syncthreads();
    }
    int excl = bbase[blockIdx.x] + sh[t] - v;
    if (i < n) {
        off[i] = excl;
        cursor[i] = excl;
        if (i == n - 1) off[n] = excl + v;
    }
}

// ---------------- CSR fill (int4 edge loads): esrc sorted by dst ----------------
__global__ void fill_kernel(const int* __restrict__ src, const int* __restrict__ dst,
                            int* __restrict__ cursor, int* __restrict__ esrc, int nE) {
    int i = blockIdx.x * blockDim.x + threadIdx.x;
    int base = i * 4;
    if (base + 4 <= nE) {
        int4 d = *(const int4*)(dst + base);
        int4 s = *(const int4*)(src + base);
        esrc[atomicAdd(&cursor[d.x], 1)] = s.x;
        esrc[atomicAdd(&cursor[d.y], 1)] = s.y;
        esrc[atomicAdd(&cursor[d.z], 1)] = s.z;
        esrc[atomicAdd(&cursor[d.w], 1)] = s.w;
    } else {
        for (int e = base; e < nE; ++e) {
            int p = atomicAdd(&cursor[dst[e]], 1);
            esrc[p] = src[e];
        }
    }
}

// ---- bf16 gather with 8/4-wide ILP: one cache line per edge row ----
__device__ __forceinline__ float gather_row_b(const ushort* __restrict__ x,
                                              const int* __restrict__ esrc,
                                              int beg, int end, int lane, float acc) {
    int i = beg;
    while (i + 8 <= end) {
        int s0 = esrc[i + 0], s1 = esrc[i + 1], s2 = esrc[i + 2], s3 = esrc[i + 3];
        int s4 = esrc[i + 4], s5 = esrc[i + 5], s6 = esrc[i + 6], s7 = esrc[i + 7];
        ushort v0 = x[(size_t)s0 * D + lane], v1 = x[(size_t)s1 * D + lane];
        ushort v2 = x[(size_t)s2 * D + lane], v3 = x[(size_t)s3 * D + lane];
        ushort v4 = x[(size_t)s4 * D + lane], v5 = x[(size_t)s5 * D + lane];
        ushort v6 = x[(size_t)s6 * D + lane], v7 = x[(size_t)s7 * D + lane];
        acc += ((b2f(v0) + b2f(v1)) + (b2f(v2) + b2f(v3))) +
               ((b2f(v4) + b2f(v5)) + (b2f(v6) + b2f(v7)));
        i += 8;
    }
    if (i + 4 <= end) {
        int s0 = esrc[i + 0], s1 = esrc[i + 1], s2 = esrc[i + 2], s3 = esrc[i + 3];
        ushort v0 = x[(size_t)s0 * D + lane], v1 = x[(size_t)s1 * D + lane];
        ushort v2 = x[(size_t)s2 * D + lane], v3 = x[(size_t)s3 * D + lane];
        acc += (b2f(v0) + b2f(v1)) + (b2f(v2) + b2f(v3));
        i += 4;
    }
    for (; i < end; ++i) acc += b2f(x[(size_t)esrc[i] * D + lane]);
    return acc;
}

// ---------------- pure gather: aggb[node] = x[node] + sum_src x[src] ----------------
// No LDS, no MLP: maximal occupancy, maximal loads in flight.
__global__ void gather_kernel(const ushort* __restrict__ xb,
                              const int* __restrict__ off,
                              const int* __restrict__ esrc,
                              ushort* __restrict__ aggb, int n) {
    int tid = threadIdx.x;
    int w = tid >> 6, lane = tid & 63;
    int node = blockIdx.x * 4 + w;
    int stride = gridDim.x * 4;
    for (; node < n; node += stride) {
        float acc = b2f(xb[(size_t)node * D + lane]);
        acc = gather_row_b(xb, esrc, off[node], off[node + 1], lane, acc);
        aggb[(size_t)node * D + lane] = f2b(acc);
    }
}

// ---------------- MFMA GEMM: hb = bf16(relu(aggb @ W1 + b1)) ----------------
// One wave per 16-node tile. B-fragments (W1 swizzled) persistent in VGPRs.
__global__ void gemm1_kernel(const ushort* __restrict__ aggb,
                             const ushort* __restrict__ Wswz,
                             const float* __restrict__ b1,
                             ushort* __restrict__ hb, int ntiles) {
    int tid = threadIdx.x;
    int w = tid >> 6, lane = tid & 63;
    int tile = blockIdx.x * 4 + w;
    if (tile >= ntiles) return;

    short8 bfrag[8];
#pragma unroll
    for (int j = 0; j < 8; ++j)
        bfrag[j] = *(const short8*)(Wswz + ((size_t)j * 64 + lane) * 8);

    int rbase = tile * 16;
    const ushort* arow = aggb + (size_t)(rbase + (lane & 15)) * D + (lane >> 4) * 8;
    short8 a0 = *(const short8*)(arow);
    short8 a1 = *(const short8*)(arow + 32);

    f32x4 acc0 = {0.f, 0.f, 0.f, 0.f};
    f32x4 acc1 = {0.f, 0.f, 0.f, 0.f};
    f32x4 acc2 = {0.f, 0.f, 0.f, 0.f};
    f32x4 acc3 = {0.f, 0.f, 0.f, 0.f};
    acc0 = __builtin_amdgcn_mfma_f32_16x16x32_bf16(a0, bfrag[0], acc0, 0, 0, 0);
    acc0 = __builtin_amdgcn_mfma_f32_16x16x32_bf16(a1, bfrag[1], acc0, 0, 0, 0);
    acc1 = __builtin_amdgcn_mfma_f32_16x16x32_bf16(a0, bfrag[2], acc1, 0, 0, 0);
    acc1 = __builtin_amdgcn_mfma_f32_16x16x32_bf16(a1, bfrag[3], acc1, 0, 0, 0);
    acc2 = __builtin_amdgcn_mfma_f32_16x16x32_bf16(a0, bfrag[4], acc2, 0, 0, 0);
    acc2 = __builtin_amdgcn_mfma_f32_16x16x32_bf16(a1, bfrag[5], acc2, 0, 0, 0);
    acc3 = __builtin_amdgcn_mfma_f32_16x16x32_bf16(a0, bfrag[6], acc3, 0, 0, 0);
    acc3 = __builtin_amdgcn_mfma_f32_16x16x32_bf16(a1, bfrag[7], acc3, 0, 0, 0);

    // C layout: col = 16c + (lane&15), row = (lane>>4)*4 + r
    int colb = lane & 15;
    int rowb = (lane >> 4) * 4;
#pragma unroll
    for (int r = 0; r < 4; ++r) {
        size_t rowoff = (size_t)(rbase + rowb + r) * D;
        hb[rowoff + colb +  0] = f2b(fmaxf(acc0[r] + b1[colb +  0], 0.f));
        hb[rowoff + colb + 16] = f2b(fmaxf(acc1[r] + b1[colb + 16], 0.f));
        hb[rowoff + colb + 32] = f2b(fmaxf(acc2[r] + b1[colb + 32], 0.f));
        hb[rowoff + colb + 48] = f2b(fmaxf(acc3[r] + b1[colb + 48], 0.f));
    }
}

// ------- gather2 + pre-GEMM pooling: P[g] = sum_{node in g} (h[node]+agg2[node]) -------
// Chunked sorted nodes; register pool accumulator, one atomicAdd per gid boundary.
__global__ void gather_pool_kernel(const ushort* __restrict__ hb,
                                   const int* __restrict__ off,
                                   const int* __restrict__ esrc,
                                   const int* __restrict__ gid,
                                   float* __restrict__ P,
                                   float* __restrict__ cntg, int n) {
    int tid = threadIdx.x;
    int w = tid >> 6, lane = tid & 63;
    int waves_total = gridDim.x * 4;
    int wave_id = blockIdx.x * 4 + w;
    int chunk = (n + waves_total - 1) / waves_total;
    int start = wave_id * chunk;
    int end = min(start + chunk, n);

    float accp = 0.f;
    int cur = -1, cnt = 0;
    for (int node = start; node < end; ++node) {
        float acc = b2f(hb[(size_t)node * D + lane]);
        acc = gather_row_b(hb, esrc, off[node], off[node + 1], lane, acc);
        int g = gid[node];            // uniform across the wave (sorted)
        if (g != cur) {
            if (cur >= 0) {
                atomicAdd(&P[cur * D + lane], accp);
                if (lane == 0) atomicAdd(&cntg[cur], (float)cnt);
            }
            cur = g; accp = 0.f; cnt = 0;
        }
        accp += acc;
        cnt++;
    }
    if (cur >= 0) {
        atomicAdd(&P[cur * D + lane], accp);
        if (lane == 0) atomicAdd(&cntg[cur], (float)cnt);
    }
}

// ------- final tiny GEMM: out[g] = P[g] @ W2 + cntg[g] * b2 (f32) -------
__global__ void final_kernel(const float* __restrict__ P,
                             const float* __restrict__ cntg,
                             const float* __restrict__ W2,
                             const float* __restrict__ b2,
                             float* __restrict__ out) {
    __shared__ float Ws[D * D];
    __shared__ float bs[D];
    __shared__ float xs[4][D];
    int tid = threadIdx.x;
    for (int i = tid; i < D * D / 4; i += blockDim.x)
        ((float4*)Ws)[i] = ((const float4*)W2)[i];
    if (tid < D) bs[tid] = b2[tid];
    __syncthreads();

    int w = tid >> 6, lane = tid & 63;
    int g = blockIdx.x * 4 + w;
    if (g >= NGRAPHS) return;
    xs[w][lane] = P[g * D + lane];
    float acc = cntg[g] * bs[lane];
#pragma unroll
    for (int k = 0; k < D; ++k)
        acc = fmaf(xs[w][k], Ws[k * D + lane], acc);
    out[g * D + lane] = acc;
}

extern "C" void kernel_launch(void* const* d_in, const int* in_sizes, int n_in,
                              void* d_out, int out_size, void* d_ws, size_t ws_size,
                              hipStream_t stream) {
    const float* feats = (const float*)d_in[0];
    const int*   src   = (const int*)d_in[1];
    const int*   dst   = (const int*)d_in[2];
    const int*   gid   = (const int*)d_in[3];
    const float* W1    = (const float*)d_in[4];
    const float* b1    = (const float*)d_in[5];
    const float* W2    = (const float*)d_in[6];
    const float* b2    = (const float*)d_in[7];
    float* out = (float*)d_out;

    int nE = in_sizes[1];
    int nBlocksN = (NNODES + 255) / 256;    // 391

    // workspace layout (all segments 16B-aligned)
    int*    cnt    = (int*)d_ws;                        // 100000 ints
    int*    off    = cnt + NNODES;                      // 100004 ints (padded)
    int*    cursor = off + 100004;                      // 100000 ints
    int*    bsum   = cursor + NNODES;                   // 400 ints
    int*    bbase  = bsum + 400;                        // 400 ints
    float*  P      = (float*)(bbase + 400);             // 128*64 f32
    float*  cntg   = P + NGRAPHS * D;                   // 128 f32 (+pad)
    int*    esrc   = (int*)(cntg + 128);                // nE ints
    ushort* Wswz   = (ushort*)(esrc + ((nE + 3) & ~3)); // 4096 bf16
    ushort* xb     = Wswz + 4096;                       // NNODES*D bf16
    ushort* aggb   = xb + (size_t)NNODES * D;           // NNODES*D bf16
    ushort* hb     = aggb + (size_t)NNODES * D;         // NNODES*D bf16

    int e4Blocks = (nE / 4 + 256) / 256;

    // ---- CSR build ----
    zero_kernel<<<256, 256, 0, stream>>>(cnt, NNODES / 4);
    hist_kernel<<<e4Blocks, 256, 0, stream>>>(dst, cnt, nE);
    partial_kernel<<<nBlocksN, 256, 0, stream>>>(cnt, bsum, NNODES);
    scanb_kernel<<<1, 512, 0, stream>>>(bsum, bbase, nBlocksN);
    offsets_kernel<<<nBlocksN, 256, 0, stream>>>(cnt, bbase, off, cursor, NNODES);
    fill_kernel<<<e4Blocks, 256, 0, stream>>>(src, dst, cursor, esrc, nE);

    // ---- prep: cast feats to bf16, swizzle W1, zero P/cntg ----
    cast_kernel<<<2048, 256, 0, stream>>>(feats, xb, NNODES * D / 4);
    prep_w_kernel<<<1, 512, 0, stream>>>(W1, Wswz);
    zero_kernel<<<8, 256, 0, stream>>>((int*)P, (NGRAPHS * D + 128) / 4);

    // ---- layer 1: gather then MFMA GEMM ----
    gather_kernel<<<2048, 256, 0, stream>>>(xb, off, esrc, aggb, NNODES);
    gemm1_kernel<<<(NTILES + 3) / 4, 256, 0, stream>>>(aggb, Wswz, b1, hb, NTILES);

    // ---- layer 2: gather + pooled pre-GEMM sum, then tiny final GEMM ----
    gather_pool_kernel<<<2048, 256, 0, stream>>>(hb, off, esrc, gid, P, cntg, NNODES);
    final_kernel<<<NGRAPHS / 4, 256, 0, stream>>>(P, cntg, W2, b2, out);
}

// Round 7
// 209.453 us; speedup vs baseline: 4.5071x; 1.3516x over previous
//
#include <hip/hip_runtime.h>

#define D 64
#define NNODES 100000
#define NGRAPHS 128
#define NTILES ((NNODES + 15) / 16)   // 6250
#define CAP 64                        // ELL row capacity (max degree; Poisson(12) -> safe)

typedef unsigned int uint;
typedef unsigned short ushort;
typedef __attribute__((ext_vector_type(8))) short short8;   // 8 bf16 (4 VGPRs)
typedef __attribute__((ext_vector_type(4))) float f32x4;

// ---- bf16 helpers (RNE) ----
__device__ __forceinline__ ushort f2b(float f) {
    uint u = __float_as_uint(f);
    uint r = (u + 0x7fffu + ((u >> 16) & 1u)) >> 16;
    return (ushort)r;
}
__device__ __forceinline__ float b2f(ushort h) {
    return __uint_as_float(((uint)h) << 16);
}

// ---------------- zero buffer (int4 grid-stride) ----------------
__global__ void zero_kernel(int* __restrict__ buf, int n4) {
    int i = blockIdx.x * blockDim.x + threadIdx.x;
    int stride = gridDim.x * blockDim.x;
    int4 z = make_int4(0, 0, 0, 0);
    for (; i < n4; i += stride) ((int4*)buf)[i] = z;
}

// ---------------- f32 -> bf16 cast (float4 in, ushort4 out) ----------------
__global__ void cast_kernel(const float* __restrict__ in, ushort* __restrict__ outb, int n4) {
    int i = blockIdx.x * blockDim.x + threadIdx.x;
    int stride = gridDim.x * blockDim.x;
    for (; i < n4; i += stride) {
        float4 v = ((const float4*)in)[i];
        ushort4 o;
        o.x = f2b(v.x); o.y = f2b(v.y); o.z = f2b(v.z); o.w = f2b(v.w);
        ((ushort4*)outb)[i] = o;
    }
}

// -------- swizzle W1 (f32 [k][col] row-major) into MFMA B-fragment order --------
__global__ void prep_w_kernel(const float* __restrict__ W, ushort* __restrict__ Wswz) {
    int t = threadIdx.x;            // 0..511 = j*64 + lane
    int j = t >> 6, lane = t & 63;
    int c = j >> 1, h = j & 1;
    int col = 16 * c + (lane & 15);
    int kbase = (lane >> 4) * 8 + 32 * h;
#pragma unroll
    for (int i = 0; i < 8; ++i)
        Wswz[(size_t)t * 8 + i] = f2b(W[(kbase + i) * D + col]);
}

// ------- fused hist+fill into ELL: ell[dst*CAP + rank] = src, rank via atomic -------
// 8 edges/thread (two int4 loads) for 8 independent atomic+store chains in flight.
__global__ void fillell_kernel(const int* __restrict__ src, const int* __restrict__ dst,
                               int* __restrict__ cnt, int* __restrict__ ell, int nE) {
    int i = blockIdx.x * blockDim.x + threadIdx.x;
    int base = i * 8;
    if (base + 8 <= nE) {
        int4 d0 = *(const int4*)(dst + base);
        int4 d1 = *(const int4*)(dst + base + 4);
        int4 s0 = *(const int4*)(src + base);
        int4 s1 = *(const int4*)(src + base + 4);
        int p0 = atomicAdd(&cnt[d0.x], 1);
        int p1 = atomicAdd(&cnt[d0.y], 1);
        int p2 = atomicAdd(&cnt[d0.z], 1);
        int p3 = atomicAdd(&cnt[d0.w], 1);
        int p4 = atomicAdd(&cnt[d1.x], 1);
        int p5 = atomicAdd(&cnt[d1.y], 1);
        int p6 = atomicAdd(&cnt[d1.z], 1);
        int p7 = atomicAdd(&cnt[d1.w], 1);
        ell[d0.x * CAP + p0] = s0.x;
        ell[d0.y * CAP + p1] = s0.y;
        ell[d0.z * CAP + p2] = s0.z;
        ell[d0.w * CAP + p3] = s0.w;
        ell[d1.x * CAP + p4] = s1.x;
        ell[d1.y * CAP + p5] = s1.y;
        ell[d1.z * CAP + p6] = s1.z;
        ell[d1.w * CAP + p7] = s1.w;
    } else {
        for (int e = base; e < nE; ++e) {
            int p = atomicAdd(&cnt[dst[e]], 1);
            ell[dst[e] * CAP + p] = src[e];
        }
    }
}

// ---- bf16 gather with 8/4-wide ILP: one cache line per edge row ----
__device__ __forceinline__ float gather_row_b(const ushort* __restrict__ x,
                                              const int* __restrict__ esrc,
                                              int beg, int end, int lane, float acc) {
    int i = beg;
    while (i + 8 <= end) {
        int s0 = esrc[i + 0], s1 = esrc[i + 1], s2 = esrc[i + 2], s3 = esrc[i + 3];
        int s4 = esrc[i + 4], s5 = esrc[i + 5], s6 = esrc[i + 6], s7 = esrc[i + 7];
        ushort v0 = x[(size_t)s0 * D + lane], v1 = x[(size_t)s1 * D + lane];
        ushort v2 = x[(size_t)s2 * D + lane], v3 = x[(size_t)s3 * D + lane];
        ushort v4 = x[(size_t)s4 * D + lane], v5 = x[(size_t)s5 * D + lane];
        ushort v6 = x[(size_t)s6 * D + lane], v7 = x[(size_t)s7 * D + lane];
        acc += ((b2f(v0) + b2f(v1)) + (b2f(v2) + b2f(v3))) +
               ((b2f(v4) + b2f(v5)) + (b2f(v6) + b2f(v7)));
        i += 8;
    }
    if (i + 4 <= end) {
        int s0 = esrc[i + 0], s1 = esrc[i + 1], s2 = esrc[i + 2], s3 = esrc[i + 3];
        ushort v0 = x[(size_t)s0 * D + lane], v1 = x[(size_t)s1 * D + lane];
        ushort v2 = x[(size_t)s2 * D + lane], v3 = x[(size_t)s3 * D + lane];
        acc += (b2f(v0) + b2f(v1)) + (b2f(v2) + b2f(v3));
        i += 4;
    }
    for (; i < end; ++i) acc += b2f(x[(size_t)esrc[i] * D + lane]);
    return acc;
}

// ---------------- pure gather (ELL): aggb[node] = x[node] + sum_src x[src] ----------------
__global__ void gather_kernel(const ushort* __restrict__ xb,
                              const int* __restrict__ cnt,
                              const int* __restrict__ ell,
                              ushort* __restrict__ aggb, int n) {
    int tid = threadIdx.x;
    int w = tid >> 6, lane = tid & 63;
    int node = blockIdx.x * 4 + w;
    int stride = gridDim.x * 4;
    for (; node < n; node += stride) {
        float acc = b2f(xb[(size_t)node * D + lane]);
        int beg = node * CAP;
        acc = gather_row_b(xb, ell, beg, beg + cnt[node], lane, acc);
        aggb[(size_t)node * D + lane] = f2b(acc);
    }
}

// ---------------- MFMA GEMM: hb = bf16(relu(aggb @ W1 + b1)) ----------------
__global__ void gemm1_kernel(const ushort* __restrict__ aggb,
                             const ushort* __restrict__ Wswz,
                             const float* __restrict__ b1,
                             ushort* __restrict__ hb, int ntiles) {
    int tid = threadIdx.x;
    int w = tid >> 6, lane = tid & 63;
    int tile = blockIdx.x * 4 + w;
    if (tile >= ntiles) return;

    short8 bfrag[8];
#pragma unroll
    for (int j = 0; j < 8; ++j)
        bfrag[j] = *(const short8*)(Wswz + ((size_t)j * 64 + lane) * 8);

    int rbase = tile * 16;
    const ushort* arow = aggb + (size_t)(rbase + (lane & 15)) * D + (lane >> 4) * 8;
    short8 a0 = *(const short8*)(arow);
    short8 a1 = *(const short8*)(arow + 32);

    f32x4 acc0 = {0.f, 0.f, 0.f, 0.f};
    f32x4 acc1 = {0.f, 0.f, 0.f, 0.f};
    f32x4 acc2 = {0.f, 0.f, 0.f, 0.f};
    f32x4 acc3 = {0.f, 0.f, 0.f, 0.f};
    acc0 = __builtin_amdgcn_mfma_f32_16x16x32_bf16(a0, bfrag[0], acc0, 0, 0, 0);
    acc0 = __builtin_amdgcn_mfma_f32_16x16x32_bf16(a1, bfrag[1], acc0, 0, 0, 0);
    acc1 = __builtin_amdgcn_mfma_f32_16x16x32_bf16(a0, bfrag[2], acc1, 0, 0, 0);
    acc1 = __builtin_amdgcn_mfma_f32_16x16x32_bf16(a1, bfrag[3], acc1, 0, 0, 0);
    acc2 = __builtin_amdgcn_mfma_f32_16x16x32_bf16(a0, bfrag[4], acc2, 0, 0, 0);
    acc2 = __builtin_amdgcn_mfma_f32_16x16x32_bf16(a1, bfrag[5], acc2, 0, 0, 0);
    acc3 = __builtin_amdgcn_mfma_f32_16x16x32_bf16(a0, bfrag[6], acc3, 0, 0, 0);
    acc3 = __builtin_amdgcn_mfma_f32_16x16x32_bf16(a1, bfrag[7], acc3, 0, 0, 0);

    // C layout: col = 16c + (lane&15), row = (lane>>4)*4 + r
    int colb = lane & 15;
    int rowb = (lane >> 4) * 4;
#pragma unroll
    for (int r = 0; r < 4; ++r) {
        size_t rowoff = (size_t)(rbase + rowb + r) * D;
        hb[rowoff + colb +  0] = f2b(fmaxf(acc0[r] + b1[colb +  0], 0.f));
        hb[rowoff + colb + 16] = f2b(fmaxf(acc1[r] + b1[colb + 16], 0.f));
        hb[rowoff + colb + 32] = f2b(fmaxf(acc2[r] + b1[colb + 32], 0.f));
        hb[rowoff + colb + 48] = f2b(fmaxf(acc3[r] + b1[colb + 48], 0.f));
    }
}

// ------- gather2 (ELL) + pre-GEMM pooling: P[g] = sum_{node in g} (h[node]+agg2[node]) -------
__global__ void gather_pool_kernel(const ushort* __restrict__ hb,
                                   const int* __restrict__ cnt,
                                   const int* __restrict__ ell,
                                   const int* __restrict__ gid,
                                   float* __restrict__ P,
                                   float* __restrict__ cntg, int n) {
    int tid = threadIdx.x;
    int w = tid >> 6, lane = tid & 63;
    int waves_total = gridDim.x * 4;
    int wave_id = blockIdx.x * 4 + w;
    int chunk = (n + waves_total - 1) / waves_total;
    int start = wave_id * chunk;
    int end = min(start + chunk, n);

    float accp = 0.f;
    int cur = -1, cc = 0;
    for (int node = start; node < end; ++node) {
        float acc = b2f(hb[(size_t)node * D + lane]);
        int beg = node * CAP;
        acc = gather_row_b(hb, ell, beg, beg + cnt[node], lane, acc);
        int g = gid[node];            // uniform across the wave (sorted)
        if (g != cur) {
            if (cur >= 0) {
                atomicAdd(&P[cur * D + lane], accp);
                if (lane == 0) atomicAdd(&cntg[cur], (float)cc);
            }
            cur = g; accp = 0.f; cc = 0;
        }
        accp += acc;
        cc++;
    }
    if (cur >= 0) {
        atomicAdd(&P[cur * D + lane], accp);
        if (lane == 0) atomicAdd(&cntg[cur], (float)cc);
    }
}

// ------- final tiny GEMM: out[g] = P[g] @ W2 + cntg[g] * b2 (f32) -------
__global__ void final_kernel(const float* __restrict__ P,
                             const float* __restrict__ cntg,
                             const float* __restrict__ W2,
                             const float* __restrict__ b2,
                             float* __restrict__ out) {
    __shared__ float Ws[D * D];
    __shared__ float bs[D];
    __shared__ float xs[4][D];
    int tid = threadIdx.x;
    for (int i = tid; i < D * D / 4; i += blockDim.x)
        ((float4*)Ws)[i] = ((const float4*)W2)[i];
    if (tid < D) bs[tid] = b2[tid];
    __syncthreads();

    int w = tid >> 6, lane = tid & 63;
    int g = blockIdx.x * 4 + w;
    if (g >= NGRAPHS) return;
    xs[w][lane] = P[g * D + lane];
    float acc = cntg[g] * bs[lane];
#pragma unroll
    for (int k = 0; k < D; ++k)
        acc = fmaf(xs[w][k], Ws[k * D + lane], acc);
    out[g * D + lane] = acc;
}

extern "C" void kernel_launch(void* const* d_in, const int* in_sizes, int n_in,
                              void* d_out, int out_size, void* d_ws, size_t ws_size,
                              hipStream_t stream) {
    const float* feats = (const float*)d_in[0];
    const int*   src   = (const int*)d_in[1];
    const int*   dst   = (const int*)d_in[2];
    const int*   gid   = (const int*)d_in[3];
    const float* W1    = (const float*)d_in[4];
    const float* b1    = (const float*)d_in[5];
    const float* W2    = (const float*)d_in[6];
    const float* b2    = (const float*)d_in[7];
    float* out = (float*)d_out;

    int nE = in_sizes[1];

    // workspace layout (all segments 16B-aligned)
    int*    cnt    = (int*)d_ws;                        // 100000 ints (+pad)
    float*  P      = (float*)(cnt + 100000);            // 128*64 f32
    float*  cntg   = P + NGRAPHS * D;                   // 128 f32
    int*    ell    = (int*)(cntg + 128);                // NNODES*CAP ints (25.6 MB)
    ushort* Wswz   = (ushort*)(ell + (size_t)NNODES * CAP); // 4096 bf16
    ushort* xb     = Wswz + 4096;                       // NNODES*D bf16
    ushort* aggb   = xb + (size_t)NNODES * D;           // NNODES*D bf16
    ushort* hb     = aggb + (size_t)NNODES * D;         // NNODES*D bf16

    int e8Blocks = (nE / 8 + 256) / 256;

    // ---- ELL build: zero counts, then one fused hist+fill edge pass ----
    zero_kernel<<<256, 256, 0, stream>>>(cnt, NNODES / 4);
    fillell_kernel<<<e8Blocks, 256, 0, stream>>>(src, dst, cnt, ell, nE);

    // ---- prep: cast feats to bf16, swizzle W1, zero P/cntg ----
    cast_kernel<<<2048, 256, 0, stream>>>(feats, xb, NNODES * D / 4);
    prep_w_kernel<<<1, 512, 0, stream>>>(W1, Wswz);
    zero_kernel<<<8, 256, 0, stream>>>((int*)P, (NGRAPHS * D + 128) / 4);

    // ---- layer 1: gather then MFMA GEMM ----
    gather_kernel<<<2048, 256, 0, stream>>>(xb, cnt, ell, aggb, NNODES);
    gemm1_kernel<<<(NTILES + 3) / 4, 256, 0, stream>>>(aggb, Wswz, b1, hb, NTILES);

    // ---- layer 2: gather + pooled pre-GEMM sum, then tiny final GEMM ----
    gather_pool_kernel<<<2048, 256, 0, stream>>>(hb, cnt, ell, gid, P, cntg, NNODES);
    final_kernel<<<NGRAPHS / 4, 256, 0, stream>>>(P, cntg, W2, b2, out);
}